// Round 3
// baseline (832.605 us; speedup 1.0000x reference)
//
#include <hip/hip_runtime.h>

// 2-layer GCN, gather formulation via device-built CSR:
//   dinv = rsqrt(1 + indeg)
//   g1 = dinv * (x @ W1)                      (norm folded into GEMM epilogue)
//   row(v) = relu(b1 + dinv[v]*(g1[v] + sum_{in} g1[src]))
//   g2[v] = dinv[v] * (row(v) @ W2)           (fused into gather1 kernel)
//   out[v] = b2 + dinv[v]*(g2[v] + sum_{in} g2[src])

constexpr int C1 = 64;
constexpr int C2 = 32;
constexpr int K1 = 768;
constexpr int SCAN_BS = 256;
constexpr int SCAN_ELEMS = 2048;   // 8 per thread
constexpr int G1_NODES = 32;       // nodes per gather1 block (8 per wave)

// ---------- edge dtype detection (device-side, graph-capture safe) ----------
__global__ void detect_k(const int* __restrict__ ei32, int* flag, int n_words) {
    __shared__ int any_nz;
    if (threadIdx.x == 0) any_nz = 0;
    __syncthreads();
    int w = 2 * threadIdx.x + 1;     // odd words = high halves if int64
    if (w < n_words && ei32[w] != 0) atomicOr(&any_nz, 1);
    __syncthreads();
    if (threadIdx.x == 0) *flag = (any_nz == 0) ? 1 : 0;
}

__device__ __forceinline__ int load_idx(const void* ei, size_t pos, int m64) {
    if (m64) return (int)((const long long*)ei)[pos];
    return ((const int*)ei)[pos];
}

// ---------- degree ----------
__global__ void zero_k(int* p, int n) {
    int i = blockIdx.x * 256 + threadIdx.x;
    if (i < n) p[i] = 0;
}

__global__ void cnt_k(const void* __restrict__ ei, const int* __restrict__ flag,
                      int* cnt, int E) {
    int e = blockIdx.x * 256 + threadIdx.x;
    if (e >= E) return;
    int m64 = *flag;
    int d = load_idx(ei, (size_t)E + e, m64);
    atomicAdd(&cnt[d], 1);
}

__global__ void dinv_k(const int* __restrict__ cnt, float* dinv, int n) {
    int i = blockIdx.x * 256 + threadIdx.x;
    if (i < n) dinv[i] = rsqrtf(1.0f + (float)cnt[i]);   // +1 self-loop
}

// ---------- block scan (exclusive) over cnt -> offsets, cursor ----------
__global__ void scan1_k(const int* __restrict__ cnt, int* partials, int n) {
    __shared__ int s[SCAN_BS];
    int base = blockIdx.x * SCAN_ELEMS;
    int t = threadIdx.x;
    int sum = 0;
    #pragma unroll
    for (int i = 0; i < 8; ++i) {
        int idx = base + t * 8 + i;
        if (idx < n) sum += cnt[idx];
    }
    s[t] = sum;
    __syncthreads();
    for (int off = 128; off > 0; off >>= 1) {
        if (t < off) s[t] += s[t + off];
        __syncthreads();
    }
    if (t == 0) partials[blockIdx.x] = s[0];
}

__global__ void scan2_k(int* partials, int* total_out, int nb) {
    __shared__ int s[256];
    int t = threadIdx.x;
    int v = (t < nb) ? partials[t] : 0;
    s[t] = v;
    __syncthreads();
    for (int off = 1; off < 256; off <<= 1) {
        int add = (t >= off) ? s[t - off] : 0;
        __syncthreads();
        s[t] += add;
        __syncthreads();
    }
    if (t < nb) partials[t] = s[t] - v;     // exclusive block offsets
    if (t == 0) *total_out = s[255];        // offsets[n]
}

__global__ void scan3_k(const int* __restrict__ cnt, const int* __restrict__ partials,
                        int* offsets, int* cursor, int n) {
    __shared__ int s[SCAN_BS];
    int base = blockIdx.x * SCAN_ELEMS;
    int t = threadIdx.x;
    int local[8];
    int sum = 0;
    #pragma unroll
    for (int i = 0; i < 8; ++i) {
        int idx = base + t * 8 + i;
        int v = (idx < n) ? cnt[idx] : 0;
        local[i] = sum;
        sum += v;
    }
    int mine = sum;
    s[t] = sum;
    __syncthreads();
    for (int off = 1; off < 256; off <<= 1) {
        int add = (t >= off) ? s[t - off] : 0;
        __syncthreads();
        s[t] += add;
        __syncthreads();
    }
    int texcl = s[t] - mine;
    int boff = partials[blockIdx.x];
    #pragma unroll
    for (int i = 0; i < 8; ++i) {
        int idx = base + t * 8 + i;
        if (idx < n) {
            int o = boff + texcl + local[i];
            offsets[idx] = o;
            cursor[idx] = o;
        }
    }
}

// ---------- CSR fill ----------
__global__ void fill_k(const void* __restrict__ ei, const int* __restrict__ flag,
                       int* cursor, int* adj, int E) {
    int e = blockIdx.x * 256 + threadIdx.x;
    if (e >= E) return;
    int m64 = *flag;
    int s = load_idx(ei, e, m64);
    int d = load_idx(ei, (size_t)E + e, m64);
    int pos = atomicAdd(&cursor[d], 1);
    adj[pos] = s;
}

// ---------- GEMM1: g1[n,64] = dinv * (x[n,768] @ W1[768,64]) ----------
// 128x64 tile, 8x4 acc per thread. As padded [32][129]: staging writes land
// on bank (k4+j+row)&31 (<=4-way on 4 banks, ~free); A-fragment reads are
// scalar b32 broadcasts (4 distinct banks x 16-lane broadcast, free).
__global__ __launch_bounds__(256) void gemm1_k(const float* __restrict__ x,
                                               const float* __restrict__ W,
                                               const float* __restrict__ dinv,
                                               float* __restrict__ g1, int n) {
    __shared__ float As[32][129];  // [k][row], pad +1
    __shared__ float Bs[32][64];   // [k][col]
    const int tid = threadIdx.x;
    const int block_row = blockIdx.x * 128;
    const int tr = tid >> 4;       // 0..15 -> rows 8*tr .. 8*tr+7
    const int tc = tid & 15;       // cols 4*tc .. 4*tc+3

    float acc[8][4] = {};

    for (int k0 = 0; k0 < K1; k0 += 32) {
        // stage A: 128 rows x 32 k = 1024 float4, 4 per thread
        #pragma unroll
        for (int i = 0; i < 4; ++i) {
            int f = tid + i * 256;           // 0..1023
            int row = f >> 3;                // 0..127
            int k4  = (f & 7) << 2;          // 0..28
            int grow = block_row + row;
            float4 v = make_float4(0.f, 0.f, 0.f, 0.f);
            if (grow < n) v = *(const float4*)(x + (size_t)grow * K1 + k0 + k4);
            As[k4 + 0][row] = v.x; As[k4 + 1][row] = v.y;
            As[k4 + 2][row] = v.z; As[k4 + 3][row] = v.w;
        }
        // stage B: 32 k x 64 cols = 512 float4, 2 per thread
        #pragma unroll
        for (int i = 0; i < 2; ++i) {
            int f = tid + i * 256;
            int kr = f >> 4;                 // 0..31
            int c4 = (f & 15) << 2;          // 0..60
            *(float4*)&Bs[kr][c4] = *(const float4*)(W + (size_t)(k0 + kr) * C1 + c4);
        }
        __syncthreads();
        #pragma unroll 8
        for (int kk = 0; kk < 32; ++kk) {
            float4 b = *(float4*)&Bs[kk][tc << 2];
            float a[8];
            #pragma unroll
            for (int i = 0; i < 8; ++i) a[i] = As[kk][(tr << 3) + i];
            #pragma unroll
            for (int i = 0; i < 8; ++i) {
                acc[i][0] += a[i] * b.x; acc[i][1] += a[i] * b.y;
                acc[i][2] += a[i] * b.z; acc[i][3] += a[i] * b.w;
            }
        }
        __syncthreads();
    }
    #pragma unroll
    for (int i = 0; i < 8; ++i) {
        int grow = block_row + (tr << 3) + i;
        if (grow < n) {
            float dv = dinv[grow];
            *(float4*)(g1 + (size_t)grow * C1 + (tc << 2)) =
                make_float4(acc[i][0] * dv, acc[i][1] * dv, acc[i][2] * dv, acc[i][3] * dv);
        }
    }
}

// ---------- layer-1 gather + fused GEMM2 ----------
// 32 nodes per block (8 sequential per wave), lane = channel. W2 staged once
// per block (amortized over 32 nodes). Neighbor loop unrolled x8 for MLP.
__global__ __launch_bounds__(256) void gather1_k(const int* __restrict__ offsets,
                                                 const int* __restrict__ adj,
                                                 const float* __restrict__ dinv,
                                                 const float* __restrict__ g1,
                                                 const float* __restrict__ b1,
                                                 const float* __restrict__ W2,
                                                 float* __restrict__ g2, int n) {
    __shared__ float sW[C1 * C2];        // 8 KB
    __shared__ float srow[G1_NODES][C1]; // 8 KB
    __shared__ float sdv[G1_NODES];
    const int tid = threadIdx.x;
    #pragma unroll
    for (int i = 0; i < (C1 * C2) / 256; ++i) sW[tid + i * 256] = W2[tid + i * 256];

    const int wid = tid >> 6;
    const int c = tid & 63;
    const int base = blockIdx.x * G1_NODES;
    const float bc = b1[c];

    #pragma unroll
    for (int i = 0; i < 8; ++i) {
        const int slot = wid * 8 + i;
        const int v = base + slot;
        float r = 0.f;
        if (v < n) {
            float dv = dinv[v];
            if (c == 0) sdv[slot] = dv;
            int start = offsets[v], end = offsets[v + 1];
            float acc = g1[(size_t)v * C1 + c];          // self-loop term
            int j = start;
            for (; j + 8 <= end; j += 8) {
                int s0 = adj[j + 0], s1 = adj[j + 1], s2 = adj[j + 2], s3 = adj[j + 3];
                int s4 = adj[j + 4], s5 = adj[j + 5], s6 = adj[j + 6], s7 = adj[j + 7];
                float a0 = g1[(size_t)s0 * C1 + c];
                float a1 = g1[(size_t)s1 * C1 + c];
                float a2 = g1[(size_t)s2 * C1 + c];
                float a3 = g1[(size_t)s3 * C1 + c];
                float a4 = g1[(size_t)s4 * C1 + c];
                float a5 = g1[(size_t)s5 * C1 + c];
                float a6 = g1[(size_t)s6 * C1 + c];
                float a7 = g1[(size_t)s7 * C1 + c];
                acc += ((a0 + a1) + (a2 + a3)) + ((a4 + a5) + (a6 + a7));
            }
            for (; j < end; ++j) acc += g1[(size_t)adj[j] * C1 + c];
            r = fmaxf(bc + dv * acc, 0.f);               // fused bias + relu
        }
        srow[slot][c] = r;
    }
    __syncthreads();

    // phase 2: h2 = relu(row) @ W2, 32 nodes x 32 ch = 1024 outputs, 4/thread
    #pragma unroll
    for (int k = 0; k < 4; ++k) {
        int idx = tid + k * 256;
        int node = idx >> 5, ch = idx & 31;
        int v = base + node;
        if (v < n) {
            float acc = 0.f;
            #pragma unroll
            for (int kk = 0; kk < C1; ++kk) acc += srow[node][kk] * sW[kk * C2 + ch];
            g2[(size_t)v * C2 + ch] = sdv[node] * acc;
        }
    }
}

// ---------- layer-2 gather (2 nodes per wave, 32 lanes each) ----------
__global__ __launch_bounds__(256) void gather2_k(const int* __restrict__ offsets,
                                                 const int* __restrict__ adj,
                                                 const float* __restrict__ dinv,
                                                 const float* __restrict__ g2,
                                                 const float* __restrict__ b2,
                                                 float* __restrict__ out, int n) {
    int v = blockIdx.x * 8 + (threadIdx.x >> 5);
    int c = threadIdx.x & 31;
    if (v >= n) return;
    int start = offsets[v], end = offsets[v + 1];
    float acc = g2[(size_t)v * C2 + c];              // self-loop term
    int j = start;
    for (; j + 8 <= end; j += 8) {
        int s0 = adj[j + 0], s1 = adj[j + 1], s2 = adj[j + 2], s3 = adj[j + 3];
        int s4 = adj[j + 4], s5 = adj[j + 5], s6 = adj[j + 6], s7 = adj[j + 7];
        float a0 = g2[(size_t)s0 * C2 + c];
        float a1 = g2[(size_t)s1 * C2 + c];
        float a2 = g2[(size_t)s2 * C2 + c];
        float a3 = g2[(size_t)s3 * C2 + c];
        float a4 = g2[(size_t)s4 * C2 + c];
        float a5 = g2[(size_t)s5 * C2 + c];
        float a6 = g2[(size_t)s6 * C2 + c];
        float a7 = g2[(size_t)s7 * C2 + c];
        acc += ((a0 + a1) + (a2 + a3)) + ((a4 + a5) + (a6 + a7));
    }
    for (; j < end; ++j) acc += g2[(size_t)adj[j] * C2 + c];
    out[(size_t)v * C2 + c] = b2[c] + dinv[v] * acc;
}

extern "C" void kernel_launch(void* const* d_in, const int* in_sizes, int n_in,
                              void* d_out, int out_size, void* d_ws, size_t ws_size,
                              hipStream_t stream) {
    const float* x  = (const float*)d_in[0];
    const void*  ei = d_in[1];
    const float* W1 = (const float*)d_in[2];
    const float* b1 = (const float*)d_in[3];
    const float* W2 = (const float*)d_in[4];
    const float* b2 = (const float*)d_in[5];
    float* out = (float*)d_out;

    const int n = in_sizes[0] / K1;     // 100000
    const int E = in_sizes[1] / 2;      // 1600000

    // workspace layout (all 4-byte types)
    float* ws      = (float*)d_ws;
    int*   flag    = (int*)ws;                      // 16-float header
    float* dinv    = ws + 16;                       // n
    float* g1      = dinv + n;                      // n*64
    float* g2      = g1 + (size_t)n * C1;           // n*32
    int*   cnt     = (int*)(g2 + (size_t)n * C2);   // n
    int*   offsets = cnt + n;                       // n+1
    int*   cursor  = offsets + n + 1;               // n
    int*   partials= cursor + n;                    // 256 (padded)
    int*   adj     = partials + 256;                // E

    const int nb_scan = (n + SCAN_ELEMS - 1) / SCAN_ELEMS;   // 49

    detect_k<<<1, 256, 0, stream>>>((const int*)ei, flag, in_sizes[1]);
    zero_k<<<(n + 255) / 256, 256, 0, stream>>>(cnt, n);
    cnt_k<<<(E + 255) / 256, 256, 0, stream>>>(ei, flag, cnt, E);
    dinv_k<<<(n + 255) / 256, 256, 0, stream>>>(cnt, dinv, n);

    gemm1_k<<<(n + 127) / 128, 256, 0, stream>>>(x, W1, dinv, g1, n);

    scan1_k<<<nb_scan, SCAN_BS, 0, stream>>>(cnt, partials, n);
    scan2_k<<<1, 256, 0, stream>>>(partials, offsets + n, nb_scan);
    scan3_k<<<nb_scan, SCAN_BS, 0, stream>>>(cnt, partials, offsets, cursor, n);
    fill_k<<<(E + 255) / 256, 256, 0, stream>>>(ei, flag, cursor, adj, E);

    gather1_k<<<(n + G1_NODES - 1) / G1_NODES, 256, 0, stream>>>(offsets, adj, dinv, g1, b1, W2, g2, n);
    gather2_k<<<(n + 7) / 8, 256, 0, stream>>>(offsets, adj, dinv, g2, b2, out, n);
}